// Round 3
// baseline (174.218 us; speedup 1.0000x reference)
//
#include <hip/hip_runtime.h>
#include <math.h>

// HPSS: S (2,1,1025,2048) fp32 non-negative.
// harm = median_31 along T (zero pad), perc = median_31 along F.
// mask_h = h^2/(h^2+p^2); out = [S*mask_h, S*mask_p] concatenated.
//
// Sliding sorted window: each thread produces R consecutive outputs along the
// median axis. Window of 31 kept SORTED in registers; per step: replace the
// departing value (exact match exists; first i with w[i]>=x_old) with the new
// one, then one forward + one backward adjacent-CE pass restores sortedness
// (array is sorted-except-one). ~185 ops/output vs ~510 for forgetful
// selection. Init via Batcher odd-even mergesort on 32 (w[31]=+INF sentinel),
// amortized over R outputs.

#define DIM_T 2048
#define DIM_F 1025
#define HALF 15
#define R 16   // outputs per thread along the sliding axis

__device__ __forceinline__ void ce(float& a, float& b) {
    const float mn = fminf(a, b);
    b = fmaxf(a, b);
    a = mn;
}

__device__ __forceinline__ void sort32(float (&a)[32]) {
#pragma unroll
    for (int p = 1; p < 32; p <<= 1) {
#pragma unroll
        for (int k = p; k >= 1; k >>= 1) {
#pragma unroll
            for (int j = k & (p - 1); j + k < 32; j += 2 * k) {
#pragma unroll
                for (int i = 0; i < k; ++i) {
                    if (i + j + k < 32) {
                        if ((i + j) / (2 * p) == (i + j + k) / (2 * p)) {
                            ce(a[i + j], a[i + j + k]);
                        }
                    }
                }
            }
        }
    }
}

// remove x_old (present exactly), insert x_new, keep w[0..30] sorted
__device__ __forceinline__ void slide(float (&w)[32], float x_old, float x_new) {
    bool prev = false;
#pragma unroll
    for (int i = 0; i < 31; ++i) {
        const bool ge = (w[i] >= x_old);
        w[i] = (ge && !prev) ? x_new : w[i];
        prev = ge;
    }
#pragma unroll
    for (int i = 0; i < 30; ++i) ce(w[i], w[i + 1]);   // fix too-big
#pragma unroll
    for (int i = 29; i >= 0; --i) ce(w[i], w[i + 1]);  // fix too-small
}

// ---------------- kernel A: harmonic medians (slide along T) ----------------
// lanes -> f (uncoalesced loads but 8KB/wave L1-resident reuse),
// harm stored TRANSPOSED harmT[b][t][f] so stores are coalesced.
__global__ __launch_bounds__(256) void harm_kernel(const float* __restrict__ S,
                                                   float* __restrict__ harmT) {
    const int f  = blockIdx.y * 256 + threadIdx.x;
    const int t0 = blockIdx.x * R;
    const int b  = blockIdx.z;
    if (f >= DIM_F) return;

    const float* __restrict__ row = S + ((size_t)b * DIM_F + f) * DIM_T;

    float w[32];
    w[31] = INFINITY;
#pragma unroll
    for (int d = 0; d < 31; ++d) {
        const int tt = t0 - HALF + d;
        w[d] = ((unsigned)tt < (unsigned)DIM_T) ? row[tt] : 0.0f;
    }
    sort32(w);

#pragma unroll
    for (int s = 0; s < R; ++s) {
        const int t = t0 + s;
        harmT[((size_t)b * DIM_T + t) * DIM_F + f] = w[15];
        const int t_rm = t - HALF, t_ad = t + HALF + 1;
        const float xo = ((unsigned)t_rm < (unsigned)DIM_T) ? row[t_rm] : 0.0f;
        const float xn = ((unsigned)t_ad < (unsigned)DIM_T) ? row[t_ad] : 0.0f;
        slide(w, xo, xn);
    }
}

// ------------- kernel B: percussive medians (slide along F) + combine -------
// lanes -> t (coalesced everything except harmT reads, which are L1-reused).
__global__ __launch_bounds__(256) void comb_kernel(const float* __restrict__ S,
                                                   const float* __restrict__ harmT,
                                                   float* __restrict__ outH,
                                                   float* __restrict__ outP) {
    const int t  = blockIdx.x * 256 + threadIdx.x;
    const int f0 = blockIdx.y * R;
    const int b  = blockIdx.z;

    const float* __restrict__ plane = S + (size_t)b * DIM_F * DIM_T + t;  // [f*T]

    float w[32];
    w[31] = INFINITY;
#pragma unroll
    for (int d = 0; d < 31; ++d) {
        const int ff = f0 - HALF + d;
        w[d] = ((unsigned)ff < (unsigned)DIM_F) ? plane[(size_t)ff * DIM_T] : 0.0f;
    }
    sort32(w);

#pragma unroll
    for (int s = 0; s < R; ++s) {
        const int f = f0 + s;
        if (f < DIM_F) {
            const float perc = w[15];
            const float harm = harmT[((size_t)b * DIM_T + t) * DIM_F + f];
            const float sc   = plane[(size_t)f * DIM_T];
            const float h2 = harm * harm;
            const float p2 = perc * perc;
            const float inv = __builtin_amdgcn_rcpf(h2 + p2);  // 0 -> +INF; 0*INF=NaN matches ref 0/0
            const size_t oi = ((size_t)b * DIM_F + f) * DIM_T + t;
            outH[oi] = sc * h2 * inv;
            outP[oi] = sc * p2 * inv;
        }
        const int f_rm = f - HALF, f_ad = f + HALF + 1;
        const float xo = ((unsigned)f_rm < (unsigned)DIM_F) ? plane[(size_t)f_rm * DIM_T] : 0.0f;
        const float xn = ((unsigned)f_ad < (unsigned)DIM_F) ? plane[(size_t)f_ad * DIM_T] : 0.0f;
        slide(w, xo, xn);
    }
}

// ---------------- fallback (ws too small): fused, forgetful harm ------------
__device__ __forceinline__ void ce2(float& a, float& b) { ce(a, b); }

template <typename Ld>
__device__ __forceinline__ float median31_forgetful(const Ld& ld) {
    float b[17];
#pragma unroll
    for (int i = 0; i < 17; ++i) b[i] = ld(i);
#pragma unroll
    for (int c = 17; c >= 4; --c) {
#pragma unroll
        for (int j = 1; j < c; ++j) ce2(b[0], b[j]);
#pragma unroll
        for (int j = 1; j < c - 1; ++j) ce2(b[j], b[c - 1]);
        b[0] = ld(34 - c);
    }
    return __builtin_amdgcn_fmed3f(b[0], b[1], b[2]);
}

__global__ __launch_bounds__(256) void fused_kernel(const float* __restrict__ S,
                                                    float* __restrict__ outH,
                                                    float* __restrict__ outP) {
    const int t  = blockIdx.x * 256 + threadIdx.x;
    const int f0 = blockIdx.y * R;
    const int b  = blockIdx.z;

    const float* __restrict__ plane = S + (size_t)b * DIM_F * DIM_T + t;

    float w[32];
    w[31] = INFINITY;
#pragma unroll
    for (int d = 0; d < 31; ++d) {
        const int ff = f0 - HALF + d;
        w[d] = ((unsigned)ff < (unsigned)DIM_F) ? plane[(size_t)ff * DIM_T] : 0.0f;
    }
    sort32(w);

#pragma unroll
    for (int s = 0; s < R; ++s) {
        const int f = f0 + s;
        if (f < DIM_F) {
            const float* __restrict__ row = S + ((size_t)b * DIM_F + f) * DIM_T;
            const float harm = median31_forgetful([&](int d) {
                const int tt = t + d - HALF;
                return ((unsigned)tt < (unsigned)DIM_T) ? row[tt] : 0.0f;
            });
            const float perc = w[15];
            const float sc   = row[t];
            const float h2 = harm * harm;
            const float p2 = perc * perc;
            const float inv = __builtin_amdgcn_rcpf(h2 + p2);
            const size_t oi = ((size_t)b * DIM_F + f) * DIM_T + t;
            outH[oi] = sc * h2 * inv;
            outP[oi] = sc * p2 * inv;
        }
        const int f_rm = f - HALF, f_ad = f + HALF + 1;
        const float xo = ((unsigned)f_rm < (unsigned)DIM_F) ? plane[(size_t)f_rm * DIM_T] : 0.0f;
        const float xn = ((unsigned)f_ad < (unsigned)DIM_F) ? plane[(size_t)f_ad * DIM_T] : 0.0f;
        slide(w, xo, xn);
    }
}

extern "C" void kernel_launch(void* const* d_in, const int* in_sizes, int n_in,
                              void* d_out, int out_size, void* d_ws, size_t ws_size,
                              hipStream_t stream) {
    const float* S = (const float*)d_in[0];
    float* outH = (float*)d_out;
    float* outP = outH + (size_t)2 * DIM_F * DIM_T;

    const size_t need = (size_t)2 * DIM_T * DIM_F * sizeof(float);
    if (ws_size >= need) {
        float* harmT = (float*)d_ws;
        dim3 gA(DIM_T / R, (DIM_F + 255) / 256, 2);
        harm_kernel<<<gA, 256, 0, stream>>>(S, harmT);
        dim3 gB(DIM_T / 256, (DIM_F + R - 1) / R, 2);
        comb_kernel<<<gB, 256, 0, stream>>>(S, harmT, outH, outP);
    } else {
        dim3 gC(DIM_T / 256, (DIM_F + R - 1) / R, 2);
        fused_kernel<<<gC, 256, 0, stream>>>(S, outH, outP);
    }
}

// Round 4
// 96.740 us; speedup vs baseline: 1.8009x; 1.8009x over previous
//
#include <hip/hip_runtime.h>
#include <math.h>

// HPSS: S (2,1,1025,2048) fp32 non-negative.
// harm = median_31 along T (zero pad), perc = median_31 along F.
// mask_h = h^2/(h^2+p^2); out = [S*mask_h, S*mask_p] concatenated.
//
// Two kernels:
//  A) harm_kernel: LDS-transposed tiles. Block stages 64(f) x 96(t) input with
//     coalesced loads, each thread slides a sorted 31-window along T from its
//     LDS row (odd stride 97 -> conflict-free), stores harmT[t][f] coalesced.
//  B) comb_kernel: lane->t (coalesced), slides sorted window along F, reads
//     harmT (L1-reused), combines and writes both outputs.
// Sliding sorted window: ~185 VALU ops/output; init Batcher-32 amortized /16.

#define DIM_T 2048
#define DIM_F 1025
#define HALF 15
#define R 16          // outputs per thread along the sliding axis
#define F_TILE 64
#define T_TILE 64
#define SPAN 96       // staged t-positions per row (need T_TILE+30 = 94)
#define LDS_STRIDE 97 // odd -> conflict-free LDS reads across fl lanes

__device__ __forceinline__ void ce(float& a, float& b) {
    const float mn = fminf(a, b);
    b = fmaxf(a, b);
    a = mn;
}

__device__ __forceinline__ void sort32(float (&a)[32]) {
#pragma unroll
    for (int p = 1; p < 32; p <<= 1) {
#pragma unroll
        for (int k = p; k >= 1; k >>= 1) {
#pragma unroll
            for (int j = k & (p - 1); j + k < 32; j += 2 * k) {
#pragma unroll
                for (int i = 0; i < k; ++i) {
                    if (i + j + k < 32) {
                        if ((i + j) / (2 * p) == (i + j + k) / (2 * p)) {
                            ce(a[i + j], a[i + j + k]);
                        }
                    }
                }
            }
        }
    }
}

// remove x_old (present exactly), insert x_new, keep w[0..30] sorted
__device__ __forceinline__ void slide(float (&w)[32], float x_old, float x_new) {
    bool prev = false;
#pragma unroll
    for (int i = 0; i < 31; ++i) {
        const bool ge = (w[i] >= x_old);
        w[i] = (ge && !prev) ? x_new : w[i];
        prev = ge;
    }
#pragma unroll
    for (int i = 0; i < 30; ++i) ce(w[i], w[i + 1]);   // fix too-big
#pragma unroll
    for (int i = 29; i >= 0; --i) ce(w[i], w[i + 1]);  // fix too-small
}

// ---------------- kernel A: harmonic medians (slide along T) ----------------
__global__ __launch_bounds__(256) void harm_kernel(const float* __restrict__ S,
                                                   float* __restrict__ harmT) {
    __shared__ float tile[F_TILE * LDS_STRIDE];
    const int tid = threadIdx.x;
    const int t0  = blockIdx.x * T_TILE;
    const int f0  = blockIdx.y * F_TILE;
    const int b   = blockIdx.z;
    const int t_in0 = t0 - HALF;

    const float* __restrict__ Sb = S + (size_t)b * DIM_F * DIM_T;

    // stage 64 rows x 96 positions, coalesced (consecutive lanes -> consecutive t)
#pragma unroll
    for (int it = 0; it < F_TILE * SPAN / 256; ++it) {   // 24 iters
        const int li  = it * 256 + tid;
        const int row = li / SPAN;
        const int pos = li - row * SPAN;
        const int f   = f0 + row;
        const int t   = t_in0 + pos;
        float v = 0.0f;
        if (f < DIM_F && (unsigned)t < (unsigned)DIM_T)
            v = Sb[(size_t)f * DIM_T + t];
        tile[row * LDS_STRIDE + pos] = v;
    }
    __syncthreads();

    const int fl    = tid & 63;
    const int chunk = tid >> 6;     // 0..3, wave-uniform
    const int tb    = chunk * R;    // local t of first output
    const float* lrow = tile + fl * LDS_STRIDE;

    float w[32];
    w[31] = INFINITY;
#pragma unroll
    for (int d = 0; d < 31; ++d) w[d] = lrow[tb + d];
    sort32(w);

    const int f = f0 + fl;
    const bool valid = (f < DIM_F);
    float* __restrict__ hb = harmT + (size_t)b * DIM_T * DIM_F;
#pragma unroll
    for (int s = 0; s < R; ++s) {
        const int t = t0 + tb + s;
        if (valid) hb[(size_t)t * DIM_F + f] = w[15];
        if (s < R - 1) {
            const float xo = lrow[tb + s];        // leaving  (t-15)
            const float xn = lrow[tb + s + 31];   // entering (t+16)
            slide(w, xo, xn);
        }
    }
}

// ------------- kernel B: percussive medians (slide along F) + combine -------
__global__ __launch_bounds__(256) void comb_kernel(const float* __restrict__ S,
                                                   const float* __restrict__ harmT,
                                                   float* __restrict__ outH,
                                                   float* __restrict__ outP) {
    const int t  = blockIdx.x * 256 + threadIdx.x;
    const int f0 = blockIdx.y * R;
    const int b  = blockIdx.z;

    const float* __restrict__ plane = S + (size_t)b * DIM_F * DIM_T + t;  // [f*T]

    float w[32];
    w[31] = INFINITY;
#pragma unroll
    for (int d = 0; d < 31; ++d) {
        const int ff = f0 - HALF + d;
        w[d] = ((unsigned)ff < (unsigned)DIM_F) ? plane[(size_t)ff * DIM_T] : 0.0f;
    }
    sort32(w);

#pragma unroll
    for (int s = 0; s < R; ++s) {
        const int f = f0 + s;
        if (f < DIM_F) {
            const float perc = w[15];
            const float harm = harmT[((size_t)b * DIM_T + t) * DIM_F + f];
            const float sc   = plane[(size_t)f * DIM_T];
            const float h2 = harm * harm;
            const float p2 = perc * perc;
            const float inv = __builtin_amdgcn_rcpf(h2 + p2);  // 0 -> INF; 0*INF=NaN matches ref 0/0
            const size_t oi = ((size_t)b * DIM_F + f) * DIM_T + t;
            outH[oi] = sc * h2 * inv;
            outP[oi] = sc * p2 * inv;
        }
        const int f_rm = f - HALF, f_ad = f + HALF + 1;
        const float xo = ((unsigned)f_rm < (unsigned)DIM_F) ? plane[(size_t)f_rm * DIM_T] : 0.0f;
        const float xn = ((unsigned)f_ad < (unsigned)DIM_F) ? plane[(size_t)f_ad * DIM_T] : 0.0f;
        slide(w, xo, xn);
    }
}

// ---------------- fallback (ws too small): fused, forgetful harm ------------
template <typename Ld>
__device__ __forceinline__ float median31_forgetful(const Ld& ld) {
    float b[17];
#pragma unroll
    for (int i = 0; i < 17; ++i) b[i] = ld(i);
#pragma unroll
    for (int c = 17; c >= 4; --c) {
#pragma unroll
        for (int j = 1; j < c; ++j) ce(b[0], b[j]);
#pragma unroll
        for (int j = 1; j < c - 1; ++j) ce(b[j], b[c - 1]);
        b[0] = ld(34 - c);
    }
    return __builtin_amdgcn_fmed3f(b[0], b[1], b[2]);
}

__global__ __launch_bounds__(256) void fused_kernel(const float* __restrict__ S,
                                                    float* __restrict__ outH,
                                                    float* __restrict__ outP) {
    const int t  = blockIdx.x * 256 + threadIdx.x;
    const int f0 = blockIdx.y * R;
    const int b  = blockIdx.z;

    const float* __restrict__ plane = S + (size_t)b * DIM_F * DIM_T + t;

    float w[32];
    w[31] = INFINITY;
#pragma unroll
    for (int d = 0; d < 31; ++d) {
        const int ff = f0 - HALF + d;
        w[d] = ((unsigned)ff < (unsigned)DIM_F) ? plane[(size_t)ff * DIM_T] : 0.0f;
    }
    sort32(w);

#pragma unroll
    for (int s = 0; s < R; ++s) {
        const int f = f0 + s;
        if (f < DIM_F) {
            const float* __restrict__ row = S + ((size_t)b * DIM_F + f) * DIM_T;
            const float harm = median31_forgetful([&](int d) {
                const int tt = t + d - HALF;
                return ((unsigned)tt < (unsigned)DIM_T) ? row[tt] : 0.0f;
            });
            const float perc = w[15];
            const float sc   = row[t];
            const float h2 = harm * harm;
            const float p2 = perc * perc;
            const float inv = __builtin_amdgcn_rcpf(h2 + p2);
            const size_t oi = ((size_t)b * DIM_F + f) * DIM_T + t;
            outH[oi] = sc * h2 * inv;
            outP[oi] = sc * p2 * inv;
        }
        const int f_rm = f - HALF, f_ad = f + HALF + 1;
        const float xo = ((unsigned)f_rm < (unsigned)DIM_F) ? plane[(size_t)f_rm * DIM_T] : 0.0f;
        const float xn = ((unsigned)f_ad < (unsigned)DIM_F) ? plane[(size_t)f_ad * DIM_T] : 0.0f;
        slide(w, xo, xn);
    }
}

extern "C" void kernel_launch(void* const* d_in, const int* in_sizes, int n_in,
                              void* d_out, int out_size, void* d_ws, size_t ws_size,
                              hipStream_t stream) {
    const float* S = (const float*)d_in[0];
    float* outH = (float*)d_out;
    float* outP = outH + (size_t)2 * DIM_F * DIM_T;

    const size_t need = (size_t)2 * DIM_T * DIM_F * sizeof(float);
    if (ws_size >= need) {
        float* harmT = (float*)d_ws;
        dim3 gA(DIM_T / T_TILE, (DIM_F + F_TILE - 1) / F_TILE, 2);   // 32 x 17 x 2
        harm_kernel<<<gA, 256, 0, stream>>>(S, harmT);
        dim3 gB(DIM_T / 256, (DIM_F + R - 1) / R, 2);
        comb_kernel<<<gB, 256, 0, stream>>>(S, harmT, outH, outP);
    } else {
        dim3 gC(DIM_T / 256, (DIM_F + R - 1) / R, 2);
        fused_kernel<<<gC, 256, 0, stream>>>(S, outH, outP);
    }
}

// Round 5
// 81.009 us; speedup vs baseline: 2.1506x; 1.1942x over previous
//
#include <hip/hip_runtime.h>
#include <math.h>

// HPSS fused: S (2,1,1025,2048) fp32 non-negative.
// harm = median_31 along T (zero pad), perc = median_31 along F.
// outH = S*h^2/(h^2+p^2), outP = S*p^2/(h^2+p^2)  (softmask Z cancels).
//
// One kernel, one block per 32(f) x 64(t) output tile:
//   stage 62x94 input tile (halo 15 both dims) in LDS, coalesced
//   phase H: 32 lanes->f x 8 t-chunks; sliding sorted 31-window along t
//            (LDS row stride 95, odd -> conflict-free); medians -> hl[32][65]
//   phase P: 64 lanes->t x 4 f-chunks of 8; sliding window along f
//            (consecutive-dword LDS reads); combine with hl, coalesced stores.
// Sliding sorted window: Batcher-32 init (amortized /8) + ~190 VALU/slide.
// __launch_bounds__(256,4): 128-VGPR cap so the 32-float window never spills
// (round-4 kernel was silently spilling at 40 VGPRs).

#define DIM_T 2048
#define DIM_F 1025
#define HALF 15
#define FT 32            // output f-rows per tile
#define TT 64            // output t-cols per tile
#define RW 8             // outputs per thread along the sliding axis
#define TROWS (FT + 30)  // 62 staged rows
#define TCOLS (TT + 30)  // 94 staged cols
#define TSTR 95          // odd stride -> conflict-free strided access
#define HSTR 65

__device__ __forceinline__ void ce(float& a, float& b) {
    const float mn = fminf(a, b);
    b = fmaxf(a, b);
    a = mn;
}

__device__ __forceinline__ void sort32(float (&a)[32]) {
#pragma unroll
    for (int p = 1; p < 32; p <<= 1) {
#pragma unroll
        for (int k = p; k >= 1; k >>= 1) {
#pragma unroll
            for (int j = k & (p - 1); j + k < 32; j += 2 * k) {
#pragma unroll
                for (int i = 0; i < k; ++i) {
                    if (i + j + k < 32) {
                        if ((i + j) / (2 * p) == (i + j + k) / (2 * p)) {
                            ce(a[i + j], a[i + j + k]);
                        }
                    }
                }
            }
        }
    }
}

// remove x_old (present in w[0..30]), insert x_new, restore sortedness
__device__ __forceinline__ void slide(float (&w)[32], float x_old, float x_new) {
    bool prev = false;
#pragma unroll
    for (int i = 0; i < 31; ++i) {
        const bool ge = (w[i] >= x_old);
        w[i] = (ge && !prev) ? x_new : w[i];
        prev = ge;
    }
#pragma unroll
    for (int i = 0; i < 30; ++i) ce(w[i], w[i + 1]);   // fix too-big
#pragma unroll
    for (int i = 29; i >= 0; --i) ce(w[i], w[i + 1]);  // fix too-small
}

__global__ __launch_bounds__(256, 4) void hpss_fused(const float* __restrict__ S,
                                                     float* __restrict__ outH,
                                                     float* __restrict__ outP) {
    __shared__ float tile[TROWS * TSTR];  // 23560 B
    __shared__ float hl[FT * HSTR];       //  8320 B

    const int tid = threadIdx.x;
    const int t0  = blockIdx.x * TT;
    const int f0  = blockIdx.y * FT;
    const int b   = blockIdx.z;
    const float* __restrict__ Sb = S + (size_t)b * DIM_F * DIM_T;

    // ---- stage 62x94 tile, coalesced (consecutive tid -> consecutive t) ----
#pragma unroll
    for (int it = 0; it < (TROWS * TCOLS + 255) / 256; ++it) {  // 23 iters
        const int li = it * 256 + tid;
        if (li < TROWS * TCOLS) {
            const int row = li / TCOLS;
            const int pos = li - row * TCOLS;
            const int f = f0 - HALF + row;
            const int t = t0 - HALF + pos;
            float v = 0.0f;
            if ((unsigned)f < (unsigned)DIM_F && (unsigned)t < (unsigned)DIM_T)
                v = Sb[(size_t)f * DIM_T + t];
            tile[row * TSTR + pos] = v;
        }
    }
    __syncthreads();

    // ---- phase H: harmonic medians (slide along t) -> hl[f][t] ----
    {
        const int fl = tid & 31;          // output f row 0..31
        const int tb = (tid >> 5) * RW;   // t chunk base 0..56
        const float* lr = tile + (fl + HALF) * TSTR;  // input row f0+fl

        float w[32];
        w[31] = INFINITY;
#pragma unroll
        for (int d = 0; d < 31; ++d) w[d] = lr[tb + d];
        sort32(w);
#pragma unroll
        for (int s = 0; s < RW; ++s) {
            hl[fl * HSTR + tb + s] = w[15];
            if (s < RW - 1) slide(w, lr[tb + s], lr[tb + s + 31]);
        }
    }
    __syncthreads();

    // ---- phase P: percussive medians (slide along f) + combine + store ----
    {
        const int lane = tid & 63;        // t within tile
        const int fb   = (tid >> 6) * RW; // f chunk base 0..24
        const int t    = t0 + lane;

        float w[32];
        w[31] = INFINITY;
#pragma unroll
        for (int d = 0; d < 31; ++d) w[d] = tile[(fb + d) * TSTR + HALF + lane];
        sort32(w);
#pragma unroll
        for (int s = 0; s < RW; ++s) {
            const int f = f0 + fb + s;
            if (f < DIM_F) {
                const float perc = w[15];
                const float harm = hl[(fb + s) * HSTR + lane];
                const float sv   = tile[(fb + s + HALF) * TSTR + HALF + lane];
                const float h2 = harm * harm;
                const float p2 = perc * perc;
                const float inv = __builtin_amdgcn_rcpf(h2 + p2);  // 0 -> INF; 0*INF=NaN matches ref 0/0
                const size_t oi = ((size_t)b * DIM_F + f) * DIM_T + t;
                outH[oi] = sv * h2 * inv;
                outP[oi] = sv * p2 * inv;
            }
            if (s < RW - 1)
                slide(w, tile[(fb + s) * TSTR + HALF + lane],
                         tile[(fb + s + 31) * TSTR + HALF + lane]);
        }
    }
}

extern "C" void kernel_launch(void* const* d_in, const int* in_sizes, int n_in,
                              void* d_out, int out_size, void* d_ws, size_t ws_size,
                              hipStream_t stream) {
    const float* S = (const float*)d_in[0];
    float* outH = (float*)d_out;
    float* outP = outH + (size_t)2 * DIM_F * DIM_T;

    dim3 grid(DIM_T / TT, (DIM_F + FT - 1) / FT, 2);  // 32 x 33 x 2
    hpss_fused<<<grid, 256, 0, stream>>>(S, outH, outP);
}

// Round 6
// 38.445 us; speedup vs baseline: 4.5317x; 2.1072x over previous
//
#include <hip/hip_runtime.h>
#include <math.h>

// HPSS fused: S (2,1,1025,2048) fp32 non-negative.
// harm = median_31 along T (zero pad), perc = median_31 along F.
// outH = S*h^2/(h^2+p^2), outP = S*p^2/(h^2+p^2)  (softmask Z cancels).
//
// One kernel, one block per 32(f) x 64(t) output tile:
//   stage 62x94 input tile (halo 15 both dims) in LDS, coalesced
//   phase H: 32 lanes->f x 8 t-chunks; sliding sorted 31-window along t
//            (LDS row stride 95, odd -> conflict-free); medians -> hl[32][65]
//   phase P: 64 lanes->t x 4 f-chunks of 8; sliding window along f
//            (stride-1 LDS reads); combine with hl, coalesced stores.
//
// Slide = delete+insert, both O(1) dependency depth (round-5 version was a
// 60-deep serial CE chain that stalled VALU issue at ~3 waves/SIMD):
//   delete: D[i] = (w[i] < x_old) ? w[i] : w[i+1]      (31 indep cmp+cndmask)
//   insert: w'[i] = v_med3(D[i-1], x_new, D[i]), w'[0] = min(x_new, D[0])
//           (31 indep v_med3_f32)
// w[31] = +INF sentinel => D[30] = INF always (x_old <= w[30] since present).
// 93 VALU/slide, depth 3, peak live ~36 floats (rolling dprev/rprev).

#define DIM_T 2048
#define DIM_F 1025
#define HALF 15
#define FT 32            // output f-rows per tile
#define TT 64            // output t-cols per tile
#define RW 8             // outputs per thread along the sliding axis
#define TROWS (FT + 30)  // 62 staged rows
#define TCOLS (TT + 30)  // 94 staged cols
#define TSTR 95          // odd stride -> conflict-free strided access
#define HSTR 65

__device__ __forceinline__ void ce(float& a, float& b) {
    const float mn = fminf(a, b);
    b = fmaxf(a, b);
    a = mn;
}

__device__ __forceinline__ void sort32(float (&a)[32]) {
#pragma unroll
    for (int p = 1; p < 32; p <<= 1) {
#pragma unroll
        for (int k = p; k >= 1; k >>= 1) {
#pragma unroll
            for (int j = k & (p - 1); j + k < 32; j += 2 * k) {
#pragma unroll
                for (int i = 0; i < k; ++i) {
                    if (i + j + k < 32) {
                        if ((i + j) / (2 * p) == (i + j + k) / (2 * p)) {
                            ce(a[i + j], a[i + j + k]);
                        }
                    }
                }
            }
        }
    }
}

// sorted-window slide: remove x_old (present in w[0..30]), insert x_new.
// w[31] must be +INF and is preserved.
__device__ __forceinline__ void slide(float (&w)[32], float x_old, float x_new) {
    float dprev = (w[0] < x_old) ? w[0] : w[1];
    float rprev = fminf(x_new, dprev);
#pragma unroll
    for (int i = 1; i < 31; ++i) {
        const float di = (w[i] < x_old) ? w[i] : w[i + 1];
        const float ri = __builtin_amdgcn_fmed3f(dprev, x_new, di);
        w[i - 1] = rprev;
        dprev = di;
        rprev = ri;
    }
    w[30] = rprev;
}

__global__ __launch_bounds__(256, 4) void hpss_fused(const float* __restrict__ S,
                                                     float* __restrict__ outH,
                                                     float* __restrict__ outP) {
    __shared__ float tile[TROWS * TSTR];  // 23560 B
    __shared__ float hl[FT * HSTR];       //  8320 B

    const int tid = threadIdx.x;
    const int t0  = blockIdx.x * TT;
    const int f0  = blockIdx.y * FT;
    const int b   = blockIdx.z;
    const float* __restrict__ Sb = S + (size_t)b * DIM_F * DIM_T;

    // ---- stage 62x94 tile, coalesced (consecutive tid -> consecutive t) ----
#pragma unroll
    for (int it = 0; it < (TROWS * TCOLS + 255) / 256; ++it) {  // 23 iters
        const int li = it * 256 + tid;
        if (li < TROWS * TCOLS) {
            const int row = li / TCOLS;
            const int pos = li - row * TCOLS;
            const int f = f0 - HALF + row;
            const int t = t0 - HALF + pos;
            float v = 0.0f;
            if ((unsigned)f < (unsigned)DIM_F && (unsigned)t < (unsigned)DIM_T)
                v = Sb[(size_t)f * DIM_T + t];
            tile[row * TSTR + pos] = v;
        }
    }
    __syncthreads();

    // ---- phase H: harmonic medians (slide along t) -> hl[f][t] ----
    {
        const int fl = tid & 31;          // output f row 0..31
        const int tb = (tid >> 5) * RW;   // t chunk base 0..56
        const float* lr = tile + (fl + HALF) * TSTR;  // input row f0+fl

        float w[32];
        w[31] = INFINITY;
#pragma unroll
        for (int d = 0; d < 31; ++d) w[d] = lr[tb + d];
        sort32(w);
#pragma unroll
        for (int s = 0; s < RW; ++s) {
            hl[fl * HSTR + tb + s] = w[15];
            if (s < RW - 1) slide(w, lr[tb + s], lr[tb + s + 31]);
        }
    }
    __syncthreads();

    // ---- phase P: percussive medians (slide along f) + combine + store ----
    {
        const int lane = tid & 63;        // t within tile
        const int fb   = (tid >> 6) * RW; // f chunk base 0..24
        const int t    = t0 + lane;

        float w[32];
        w[31] = INFINITY;
#pragma unroll
        for (int d = 0; d < 31; ++d) w[d] = tile[(fb + d) * TSTR + HALF + lane];
        sort32(w);
#pragma unroll
        for (int s = 0; s < RW; ++s) {
            const int f = f0 + fb + s;
            if (f < DIM_F) {
                const float perc = w[15];
                const float harm = hl[(fb + s) * HSTR + lane];
                const float sv   = tile[(fb + s + HALF) * TSTR + HALF + lane];
                const float h2 = harm * harm;
                const float p2 = perc * perc;
                const float inv = __builtin_amdgcn_rcpf(h2 + p2);  // 0 -> INF; 0*INF=NaN matches ref 0/0
                const size_t oi = ((size_t)b * DIM_F + f) * DIM_T + t;
                outH[oi] = sv * h2 * inv;
                outP[oi] = sv * p2 * inv;
            }
            if (s < RW - 1)
                slide(w, tile[(fb + s) * TSTR + HALF + lane],
                         tile[(fb + s + 31) * TSTR + HALF + lane]);
        }
    }
}

extern "C" void kernel_launch(void* const* d_in, const int* in_sizes, int n_in,
                              void* d_out, int out_size, void* d_ws, size_t ws_size,
                              hipStream_t stream) {
    const float* S = (const float*)d_in[0];
    float* outH = (float*)d_out;
    float* outP = outH + (size_t)2 * DIM_F * DIM_T;

    dim3 grid(DIM_T / TT, (DIM_F + FT - 1) / FT, 2);  // 32 x 33 x 2
    hpss_fused<<<grid, 256, 0, stream>>>(S, outH, outP);
}

// Round 7
// 38.358 us; speedup vs baseline: 4.5419x; 1.0023x over previous
//
#include <hip/hip_runtime.h>
#include <math.h>

// HPSS fused, fp16 LDS edition. S (2,1,1025,2048) fp32 non-negative.
// harm = median_31 along T (zero pad), perc = median_31 along F.
// outH = S*h^2/(h^2+p^2), outP = S*p^2/(h^2+p^2)   (softmask Z cancels).
//
// Key fact: fp16 rounding is monotone => median(fp16(x)) == fp16(median(x)).
// So the whole sort/slide pipeline runs in scalar fp16 (v_min/max/med3_f16,
// full rate, same instr count as f32) with HALF the LDS:
//   tile fp16 62x98-stride (12.2KB) + hl fp16 32x66-stride (4.2KB) = 16.4KB
//   -> 8 blocks/CU (wave-cap), 100% occupancy ceiling (round-6: 32KB -> 5
//      blocks, 62% ceiling, measured 34% -> latency-bound at 44% VALUBusy).
// Exact fp32 S multiplier re-read from global in the combine (coalesced).
// Slide = delete+insert at O(1) dependency depth:
//   D[i] = (w[i] < x_old) ? w[i] : w[i+1]; w'[i] = med3(D[i-1], x_new, D[i]).

#define DIM_T 2048
#define DIM_F 1025
#define HALF 15
#define FT 32            // output f-rows per tile
#define TT 64            // output t-cols per tile
#define RW 8             // outputs per thread along the sliding axis
#define TROWS (FT + 30)  // 62 staged rows
#define TCOLS (TT + 30)  // 94 staged cols
#define TSTR 98          // halves; 49 dwords (odd) -> conflict-free strided reads
#define HSTR 66          // halves; 33 dwords (odd)

typedef _Float16 h16;

__device__ __forceinline__ h16 hmin(h16 a, h16 b) {
#if __has_builtin(__builtin_fminf16)
    return __builtin_fminf16(a, b);
#else
    return a < b ? a : b;
#endif
}
__device__ __forceinline__ h16 hmax(h16 a, h16 b) {
#if __has_builtin(__builtin_fmaxf16)
    return __builtin_fmaxf16(a, b);
#else
    return a > b ? a : b;
#endif
}
__device__ __forceinline__ h16 hmed3(h16 a, h16 b, h16 c) {
#if __has_builtin(__builtin_amdgcn_fmed3h)
    return __builtin_amdgcn_fmed3h(a, b, c);
#else
    return hmax(hmin(a, b), hmin(hmax(a, b), c));
#endif
}

__device__ __forceinline__ void ce(h16& a, h16& b) {
    const h16 mn = hmin(a, b);
    b = hmax(a, b);
    a = mn;
}

__device__ __forceinline__ void sort32(h16 (&a)[32]) {
#pragma unroll
    for (int p = 1; p < 32; p <<= 1) {
#pragma unroll
        for (int k = p; k >= 1; k >>= 1) {
#pragma unroll
            for (int j = k & (p - 1); j + k < 32; j += 2 * k) {
#pragma unroll
                for (int i = 0; i < k; ++i) {
                    if (i + j + k < 32) {
                        if ((i + j) / (2 * p) == (i + j + k) / (2 * p)) {
                            ce(a[i + j], a[i + j + k]);
                        }
                    }
                }
            }
        }
    }
}

// sorted-window slide: remove x_old (present in w[0..30]), insert x_new.
// w[31] must be +INF and is preserved. 31 indep (cmp+sel), 31 indep med3.
__device__ __forceinline__ void slide(h16 (&w)[32], h16 x_old, h16 x_new) {
    h16 dprev = (w[0] < x_old) ? w[0] : w[1];
    h16 rprev = hmin(x_new, dprev);
#pragma unroll
    for (int i = 1; i < 31; ++i) {
        const h16 di = (w[i] < x_old) ? w[i] : w[i + 1];
        const h16 ri = hmed3(dprev, x_new, di);
        w[i - 1] = rprev;
        dprev = di;
        rprev = ri;
    }
    w[30] = rprev;
}

__global__ __launch_bounds__(256, 8) void hpss_fused(const float* __restrict__ S,
                                                     float* __restrict__ outH,
                                                     float* __restrict__ outP) {
    __shared__ h16 tile[TROWS * TSTR];  // 12152 B
    __shared__ h16 hl[FT * HSTR];       //  4224 B

    const int tid = threadIdx.x;
    const int t0  = blockIdx.x * TT;
    const int f0  = blockIdx.y * FT;
    const int b   = blockIdx.z;
    const float* __restrict__ Sb = S + (size_t)b * DIM_F * DIM_T;

    // ---- stage 62x94 tile as fp16, coalesced (consecutive tid -> t) ----
    const bool interior = (blockIdx.x != 0) & (blockIdx.x != gridDim.x - 1) &
                          (f0 >= HALF) & (f0 + FT + HALF <= DIM_F);
    if (interior) {
#pragma unroll
        for (int it = 0; it < (TROWS * TCOLS + 255) / 256; ++it) {  // 23 iters
            const int li = it * 256 + tid;
            if (li < TROWS * TCOLS) {
                const int row = li / TCOLS;
                const int pos = li - row * TCOLS;
                tile[row * TSTR + pos] =
                    (h16)Sb[(size_t)(f0 - HALF + row) * DIM_T + (t0 - HALF + pos)];
            }
        }
    } else {
#pragma unroll
        for (int it = 0; it < (TROWS * TCOLS + 255) / 256; ++it) {
            const int li = it * 256 + tid;
            if (li < TROWS * TCOLS) {
                const int row = li / TCOLS;
                const int pos = li - row * TCOLS;
                const int f = f0 - HALF + row;
                const int t = t0 - HALF + pos;
                float v = 0.0f;
                if ((unsigned)f < (unsigned)DIM_F && (unsigned)t < (unsigned)DIM_T)
                    v = Sb[(size_t)f * DIM_T + t];
                tile[row * TSTR + pos] = (h16)v;
            }
        }
    }
    __syncthreads();

    // ---- phase H: harmonic medians (slide along t) -> hl[f][t] ----
    {
        const int fl = tid & 31;          // output f row 0..31
        const int tb = (tid >> 5) * RW;   // t chunk base 0..56
        const h16* lr = tile + (fl + HALF) * TSTR;  // input row f0+fl

        h16 w[32];
        w[31] = (h16)INFINITY;
#pragma unroll
        for (int d = 0; d < 31; ++d) w[d] = lr[tb + d];
        sort32(w);
#pragma unroll
        for (int s = 0; s < RW; ++s) {
            hl[fl * HSTR + tb + s] = w[15];
            if (s < RW - 1) slide(w, lr[tb + s], lr[tb + s + 31]);
        }
    }
    __syncthreads();

    // ---- phase P: percussive medians (slide along f) + combine + store ----
    {
        const int lane = tid & 63;        // t within tile
        const int fb   = (tid >> 6) * RW; // f chunk base 0..24
        const int t    = t0 + lane;

        h16 w[32];
        w[31] = (h16)INFINITY;
#pragma unroll
        for (int d = 0; d < 31; ++d) w[d] = tile[(fb + d) * TSTR + HALF + lane];
        sort32(w);
#pragma unroll
        for (int s = 0; s < RW; ++s) {
            const int f = f0 + fb + s;
            if (f < DIM_F) {
                const float perc = (float)w[15];
                const float harm = (float)hl[(fb + s) * HSTR + lane];
                const float sv   = Sb[(size_t)f * DIM_T + t];   // exact fp32 S
                const float h2 = harm * harm;
                const float p2 = perc * perc;
                const float inv = __builtin_amdgcn_rcpf(h2 + p2);  // 0 -> INF; 0*INF=NaN matches ref 0/0
                const size_t oi = ((size_t)b * DIM_F + f) * DIM_T + t;
                outH[oi] = sv * h2 * inv;
                outP[oi] = sv * p2 * inv;
            }
            if (s < RW - 1)
                slide(w, tile[(fb + s) * TSTR + HALF + lane],
                         tile[(fb + s + 31) * TSTR + HALF + lane]);
        }
    }
}

extern "C" void kernel_launch(void* const* d_in, const int* in_sizes, int n_in,
                              void* d_out, int out_size, void* d_ws, size_t ws_size,
                              hipStream_t stream) {
    const float* S = (const float*)d_in[0];
    float* outH = (float*)d_out;
    float* outP = outH + (size_t)2 * DIM_F * DIM_T;

    dim3 grid(DIM_T / TT, (DIM_F + FT - 1) / FT, 2);  // 32 x 33 x 2
    hpss_fused<<<grid, 256, 0, stream>>>(S, outH, outP);
}